// Round 1
// baseline (1380.272 us; speedup 1.0000x reference)
//
#include <hip/hip_runtime.h>
#include <hip/hip_bf16.h>
#include <math.h>

#define B_ 4
#define T_ 128
#define C_ 128
#define HW_ 576
#define G_ 128
#define P_ 32
#define NH_ 4
#define HD_ 32
#define FF_ 512
#define EPS_ATTN 1e-6f
#define EPS_LN 1e-5f

#define TOK 64          // tokens (pixels) per block
#define XS_STRIDE 68    // padded LDS stride (floats), 16B-aligned, breaks bank cycles
#define HS_STRIDE 68
#define CHUNK 64        // FFN hidden chunk

// ---------------------------------------------------------------------------
// Kernel A: prototype K/V -> KV (H,D,D) and ksum (H,D) into ws
// ws layout: [0,4096) KV flat h*1024+d*32+dv ; [4096,4224) ksum flat h*32+d
// ---------------------------------------------------------------------------
__global__ __launch_bounds__(1024)
void proto_kernel(const float* __restrict__ protos,
                  const float* __restrict__ Wk, const float* __restrict__ bk,
                  const float* __restrict__ Wv, const float* __restrict__ bv,
                  float* __restrict__ ws) {
    __shared__ float kf_s[P_][C_];
    __shared__ float vv_s[P_][C_];
    int tid = threadIdx.x;
    for (int idx = tid; idx < P_ * C_; idx += 1024) {
        int p = idx >> 7, c = idx & 127;
        const float* pr  = protos + p * C_;
        const float* wkr = Wk + (size_t)c * C_;
        const float* wvr = Wv + (size_t)c * C_;
        float ka = bk[c], va = bv[c];
        for (int j = 0; j < C_; j += 4) {
            float4 pv  = *(const float4*)(pr + j);
            float4 wk4 = *(const float4*)(wkr + j);
            float4 wv4 = *(const float4*)(wvr + j);
            ka = fmaf(pv.x, wk4.x, ka); ka = fmaf(pv.y, wk4.y, ka);
            ka = fmaf(pv.z, wk4.z, ka); ka = fmaf(pv.w, wk4.w, ka);
            va = fmaf(pv.x, wv4.x, va); va = fmaf(pv.y, wv4.y, va);
            va = fmaf(pv.z, wv4.z, va); va = fmaf(pv.w, wv4.w, va);
        }
        // kf = elu(k)+1 ; vv = v / P
        kf_s[p][c] = ka > 0.f ? ka + 1.f : expf(ka);
        vv_s[p][c] = va * (1.f / P_);
    }
    __syncthreads();
    for (int idx = tid; idx < NH_ * HD_ * HD_; idx += 1024) {
        int h = idx >> 10, d = (idx >> 5) & 31, dv = idx & 31;
        float acc = 0.f;
        for (int p = 0; p < P_; ++p)
            acc = fmaf(kf_s[p][h * HD_ + d], vv_s[p][h * HD_ + dv], acc);
        ws[idx] = acc;
    }
    if (tid < C_) {
        float acc = 0.f;
        for (int p = 0; p < P_; ++p) acc += kf_s[p][tid];
        ws[4096 + tid] = acc;
    }
}

// ---------------------------------------------------------------------------
// Main fused kernel: 64 pixels of one (b,t) per block, 256 threads.
// ---------------------------------------------------------------------------
__global__ __launch_bounds__(256)
void cat_main_kernel(const float* __restrict__ x, const float* __restrict__ guid,
                     const float* __restrict__ Wq, const float* __restrict__ bq,
                     const float* __restrict__ ln1_g, const float* __restrict__ ln1_b,
                     const float* __restrict__ ln2_g, const float* __restrict__ ln2_b,
                     const float* __restrict__ W1, const float* __restrict__ b1,
                     const float* __restrict__ W2, const float* __restrict__ b2,
                     const float* __restrict__ ws, float* __restrict__ out) {
    __shared__ float xs[C_][XS_STRIDE];      // x tile -> qf -> out1 -> y (LN2)
    __shared__ float hs[CHUNK][HS_STRIDE];   // FFN hidden chunk
    __shared__ float qgs[C_];                // guidance part of q (+bq)
    __shared__ float gus[G_];
    __shared__ float mu1[TOK], rs1[TOK], mu2[TOK], rs2[TOK];
    __shared__ float zs[NH_][TOK];

    const int tid = threadIdx.x;
    const int t = blockIdx.y, b = blockIdx.z;
    const int hw0 = blockIdx.x * TOK;
    const size_t slab = (size_t)(b * T_ + t) * C_;   // row base; rows have length HW_
    const float* xbase = x + slab * HW_ + hw0;

    // ---- stage x tile (coalesced: 128B per lane) ----
    {
        int row = tid >> 1, half = tid & 1;
        const float* src = xbase + (size_t)row * HW_ + half * 32;
        float* dst = &xs[row][half * 32];
        #pragma unroll
        for (int i = 0; i < 8; ++i)
            *(float4*)(dst + i * 4) = *(const float4*)(src + i * 4);
    }
    if (tid < G_) gus[tid] = guid[(size_t)(b * T_ + t) * G_ + tid];
    __syncthreads();

    // ---- LN1 stats: 4 threads per token ----
    {
        int tok = tid >> 2, i = tid & 3;
        float s = 0.f, s2 = 0.f;
        for (int c = i; c < C_; c += 4) {
            float v = xs[c][tok];
            s += v; s2 = fmaf(v, v, s2);
        }
        s += __shfl_xor(s, 1); s2 += __shfl_xor(s2, 1);
        s += __shfl_xor(s, 2); s2 += __shfl_xor(s2, 2);
        if (i == 0) {
            float mu = s * (1.f / C_);
            float var = s2 * (1.f / C_) - mu * mu;
            mu1[tok] = mu;
            rs1[tok] = rsqrtf(var + EPS_LN);
        }
    }
    // ---- guidance projection qg[c] = bq[c] + sum_g guid[g]*Wq[c][128+g] ----
    if (tid < C_) {
        const float* wr = Wq + (size_t)tid * (C_ + G_) + C_;
        float acc = bq[tid];
        for (int g = 0; g < G_; g += 4) {
            float4 w4 = *(const float4*)(wr + g);
            acc = fmaf(gus[g],     w4.x, acc);
            acc = fmaf(gus[g + 1], w4.y, acc);
            acc = fmaf(gus[g + 2], w4.z, acc);
            acc = fmaf(gus[g + 3], w4.w, acc);
        }
        qgs[tid] = acc;
    }
    __syncthreads();

    const int tokg = (tid & 7) * 8;        // 8 tokens per thread
    const int c0   = (tid >> 3) * 4;       // 4 channels per thread

    // ---- Q projection (x part) + LN1 values, register tile 4c x 8tok ----
    float qv[4][8];
    float ln1v[4][8];
    {
        #pragma unroll
        for (int ci = 0; ci < 4; ++ci) {
            float qg = qgs[c0 + ci];
            #pragma unroll
            for (int tk = 0; tk < 8; ++tk) qv[ci][tk] = qg;
        }
        for (int k = 0; k < C_; k += 4) {
            float4 w[4];
            #pragma unroll
            for (int ci = 0; ci < 4; ++ci)
                w[ci] = *(const float4*)(Wq + (size_t)(c0 + ci) * (C_ + G_) + k);
            #pragma unroll
            for (int kk = 0; kk < 4; ++kk) {
                const float4* xr = (const float4*)&xs[k + kk][tokg];
                float4 xa = xr[0], xb = xr[1];
                float xv[8] = {xa.x, xa.y, xa.z, xa.w, xb.x, xb.y, xb.z, xb.w};
                #pragma unroll
                for (int ci = 0; ci < 4; ++ci) {
                    float wv = ((const float*)&w[ci])[kk];
                    #pragma unroll
                    for (int tk = 0; tk < 8; ++tk)
                        qv[ci][tk] = fmaf(wv, xv[tk], qv[ci][tk]);
                }
            }
        }
        #pragma unroll
        for (int ci = 0; ci < 4; ++ci) {
            float g1 = ln1_g[c0 + ci], bb = ln1_b[c0 + ci];
            #pragma unroll
            for (int tk = 0; tk < 8; ++tk) {
                float v = xs[c0 + ci][tokg + tk];
                ln1v[ci][tk] = fmaf((v - mu1[tokg + tk]) * rs1[tokg + tk], g1, bb);
            }
        }
    }
    __syncthreads();
    // ---- overwrite xs with qf = elu(q)+1 ----
    #pragma unroll
    for (int ci = 0; ci < 4; ++ci) {
        #pragma unroll
        for (int tk = 0; tk < 8; ++tk) {
            float q = qv[ci][tk];
            xs[c0 + ci][tokg + tk] = q > 0.f ? q + 1.f : expf(q);
        }
    }
    __syncthreads();

    // ---- Z = P / (qf . ksum + eps) ----
    {
        int tok = tid & 63, h = tid >> 6;
        const float* ksum = ws + 4096 + h * HD_;
        float acc = 0.f;
        for (int d = 0; d < HD_; ++d)
            acc = fmaf(xs[h * HD_ + d][tok], ksum[d], acc);
        zs[h][tok] = (float)P_ / (acc + EPS_ATTN);
    }
    __syncthreads();

    // ---- attention output + residual LN1 -> out1 (registers) ----
    float o1[4][8];
    {
        int h = c0 >> 5;
        int dv0 = c0 & 31;
        float acc[4][8];
        #pragma unroll
        for (int ci = 0; ci < 4; ++ci)
            #pragma unroll
            for (int tk = 0; tk < 8; ++tk) acc[ci][tk] = 0.f;
        const float* KV = ws + h * HD_ * HD_;
        for (int d = 0; d < HD_; ++d) {
            float4 kv4 = *(const float4*)(KV + d * HD_ + dv0);
            const float4* xr = (const float4*)&xs[h * HD_ + d][tokg];
            float4 xa = xr[0], xb = xr[1];
            float qf[8] = {xa.x, xa.y, xa.z, xa.w, xb.x, xb.y, xb.z, xb.w};
            #pragma unroll
            for (int tk = 0; tk < 8; ++tk) {
                acc[0][tk] = fmaf(qf[tk], kv4.x, acc[0][tk]);
                acc[1][tk] = fmaf(qf[tk], kv4.y, acc[1][tk]);
                acc[2][tk] = fmaf(qf[tk], kv4.z, acc[2][tk]);
                acc[3][tk] = fmaf(qf[tk], kv4.w, acc[3][tk]);
            }
        }
        #pragma unroll
        for (int tk = 0; tk < 8; ++tk) {
            float z = zs[h][tokg + tk];
            #pragma unroll
            for (int ci = 0; ci < 4; ++ci)
                o1[ci][tk] = fmaf(acc[ci][tk], z, ln1v[ci][tk]);
        }
    }
    __syncthreads();
    // ---- out1 -> xs ----
    #pragma unroll
    for (int ci = 0; ci < 4; ++ci)
        #pragma unroll
        for (int tk = 0; tk < 8; ++tk)
            xs[c0 + ci][tokg + tk] = o1[ci][tk];
    __syncthreads();

    // ---- LN2 stats ----
    {
        int tok = tid >> 2, i = tid & 3;
        float s = 0.f, s2 = 0.f;
        for (int c = i; c < C_; c += 4) {
            float v = xs[c][tok];
            s += v; s2 = fmaf(v, v, s2);
        }
        s += __shfl_xor(s, 1); s2 += __shfl_xor(s2, 1);
        s += __shfl_xor(s, 2); s2 += __shfl_xor(s2, 2);
        if (i == 0) {
            float mu = s * (1.f / C_);
            float var = s2 * (1.f / C_) - mu * mu;
            mu2[tok] = mu;
            rs2[tok] = rsqrtf(var + EPS_LN);
        }
    }
    __syncthreads();
    // ---- y = LN2(out1) in place (own elements, from registers) ----
    #pragma unroll
    for (int ci = 0; ci < 4; ++ci) {
        float g2 = ln2_g[c0 + ci], bb = ln2_b[c0 + ci];
        #pragma unroll
        for (int tk = 0; tk < 8; ++tk)
            xs[c0 + ci][tokg + tk] =
                fmaf((o1[ci][tk] - mu2[tokg + tk]) * rs2[tokg + tk], g2, bb);
    }
    __syncthreads();

    // ---- FFN: 8 chunks of 64 hidden units through LDS ----
    float facc[4][8];
    #pragma unroll
    for (int ci = 0; ci < 4; ++ci)
        #pragma unroll
        for (int tk = 0; tk < 8; ++tk) facc[ci][tk] = 0.f;

    const int jl0 = (tid >> 3) * 2;   // 2 hidden units per thread per chunk
    for (int chunk = 0; chunk < FF_ / CHUNK; ++chunk) {
        const int j0 = chunk * CHUNK;
        float a0[8], a1[8];
        {
            float bb0 = b1[j0 + jl0], bb1 = b1[j0 + jl0 + 1];
            #pragma unroll
            for (int tk = 0; tk < 8; ++tk) { a0[tk] = bb0; a1[tk] = bb1; }
            const float* w1r0 = W1 + (size_t)(j0 + jl0) * C_;
            const float* w1r1 = w1r0 + C_;
            for (int c = 0; c < C_; c += 4) {
                float4 w0 = *(const float4*)(w1r0 + c);
                float4 w1v = *(const float4*)(w1r1 + c);
                #pragma unroll
                for (int kk = 0; kk < 4; ++kk) {
                    const float4* xr = (const float4*)&xs[c + kk][tokg];
                    float4 xa = xr[0], xb = xr[1];
                    float xv[8] = {xa.x, xa.y, xa.z, xa.w, xb.x, xb.y, xb.z, xb.w};
                    float w0k = ((const float*)&w0)[kk];
                    float w1k = ((const float*)&w1v)[kk];
                    #pragma unroll
                    for (int tk = 0; tk < 8; ++tk) {
                        a0[tk] = fmaf(w0k, xv[tk], a0[tk]);
                        a1[tk] = fmaf(w1k, xv[tk], a1[tk]);
                    }
                }
            }
        }
        // exact GELU, write chunk
        #pragma unroll
        for (int tk = 0; tk < 8; ++tk) {
            float v0 = a0[tk], v1 = a1[tk];
            hs[jl0][tokg + tk]     = 0.5f * v0 * (1.f + erff(v0 * 0.70710678118654752f));
            hs[jl0 + 1][tokg + tk] = 0.5f * v1 * (1.f + erff(v1 * 0.70710678118654752f));
        }
        __syncthreads();
        // accumulate chunk into ffn output
        {
            const float* w2r0 = W2 + (size_t)(c0 + 0) * FF_ + j0;
            const float* w2r1 = W2 + (size_t)(c0 + 1) * FF_ + j0;
            const float* w2r2 = W2 + (size_t)(c0 + 2) * FF_ + j0;
            const float* w2r3 = W2 + (size_t)(c0 + 3) * FF_ + j0;
            for (int j = 0; j < CHUNK; j += 4) {
                float4 w[4];
                w[0] = *(const float4*)(w2r0 + j);
                w[1] = *(const float4*)(w2r1 + j);
                w[2] = *(const float4*)(w2r2 + j);
                w[3] = *(const float4*)(w2r3 + j);
                #pragma unroll
                for (int kk = 0; kk < 4; ++kk) {
                    const float4* hr = (const float4*)&hs[j + kk][tokg];
                    float4 ha = hr[0], hb = hr[1];
                    float hv[8] = {ha.x, ha.y, ha.z, ha.w, hb.x, hb.y, hb.z, hb.w};
                    #pragma unroll
                    for (int ci = 0; ci < 4; ++ci) {
                        float wv = ((const float*)&w[ci])[kk];
                        #pragma unroll
                        for (int tk = 0; tk < 8; ++tk)
                            facc[ci][tk] = fmaf(wv, hv[tk], facc[ci][tk]);
                    }
                }
            }
        }
        __syncthreads();
    }

    // ---- final: out = out1 + ffn + b2, store (coalesced rows) ----
    float* obase = out + slab * HW_ + hw0;
    #pragma unroll
    for (int ci = 0; ci < 4; ++ci) {
        float bb = b2[c0 + ci];
        float tmp[8];
        #pragma unroll
        for (int tk = 0; tk < 8; ++tk)
            tmp[tk] = o1[ci][tk] + facc[ci][tk] + bb;
        float* dst = obase + (size_t)(c0 + ci) * HW_ + tokg;
        *(float4*)(dst)     = make_float4(tmp[0], tmp[1], tmp[2], tmp[3]);
        *(float4*)(dst + 4) = make_float4(tmp[4], tmp[5], tmp[6], tmp[7]);
    }
}

extern "C" void kernel_launch(void* const* d_in, const int* in_sizes, int n_in,
                              void* d_out, int out_size, void* d_ws, size_t ws_size,
                              hipStream_t stream) {
    (void)in_sizes; (void)n_in; (void)out_size; (void)ws_size;
    const float* x      = (const float*)d_in[0];
    const float* guid   = (const float*)d_in[1];
    const float* protos = (const float*)d_in[2];
    const float* Wq     = (const float*)d_in[3];
    const float* bq     = (const float*)d_in[4];
    const float* Wk     = (const float*)d_in[5];
    const float* bk     = (const float*)d_in[6];
    const float* Wv     = (const float*)d_in[7];
    const float* bv     = (const float*)d_in[8];
    const float* ln1_g  = (const float*)d_in[9];
    const float* ln1_b  = (const float*)d_in[10];
    const float* ln2_g  = (const float*)d_in[11];
    const float* ln2_b  = (const float*)d_in[12];
    const float* W1     = (const float*)d_in[13];
    const float* b1     = (const float*)d_in[14];
    const float* W2     = (const float*)d_in[15];
    const float* b2     = (const float*)d_in[16];
    float* out = (float*)d_out;
    float* ws  = (float*)d_ws;

    proto_kernel<<<1, 1024, 0, stream>>>(protos, Wk, bk, Wv, bv, ws);
    dim3 grid(HW_ / TOK, T_, B_);
    cat_main_kernel<<<grid, 256, 0, stream>>>(x, guid, Wq, bq,
                                              ln1_g, ln1_b, ln2_g, ln2_b,
                                              W1, b1, W2, b2, ws, out);
}

// Round 2
// 643.864 us; speedup vs baseline: 2.1437x; 2.1437x over previous
//
#include <hip/hip_runtime.h>
#include <math.h>

#define B_ 4
#define T_ 128
#define C_ 128
#define HW_ 576
#define P_ 32
#define FF_ 512
#define EPS_ATTN 1e-6f
#define EPS_LN 1e-5f
#define TOK 64

typedef __bf16 bf16x8 __attribute__((ext_vector_type(8)));
typedef float f32x4 __attribute__((ext_vector_type(4)));
typedef short s16x8 __attribute__((ext_vector_type(8)));

// ---- ws byte offsets (all 16B aligned) ----
#define WS_KVT   0        // bf16 [128][32]   : kvT[col][d] = KV[col>>5][d][col&31]
#define WS_KSUM  8192     // f32  [128]
#define WS_WQX   8704     // bf16 [128][128]  : x-part of Wq, row-major [out][k]
#define WS_W1    41472    // bf16 [512][128]
#define WS_W2    172544   // bf16 [128][512]
#define WS_QG    303616   // f32  [512][128]  : per-(b,t) guidance projection + bq

__device__ __forceinline__ short f2b(float f) {
    unsigned u = __builtin_bit_cast(unsigned, f);
    u = (u + 0x7fffu + ((u >> 16) & 1u)) >> 16;
    return (short)u;
}
__device__ __forceinline__ float b2f(short s) {
    return __builtin_bit_cast(float, ((unsigned)(unsigned short)s) << 16);
}
// swizzled short-index into a [64][128] bf16 tile: XOR 16B-granule by (row&7)
__device__ __forceinline__ int swz(int row, int col) {
    return (row << 7) | (col ^ ((row & 7) << 3));
}

// ---------------------------------------------------------------------------
// prep 1: prototypes -> kvT (bf16) + ksum (f32)
// ---------------------------------------------------------------------------
__global__ __launch_bounds__(1024)
void prep_proto(const float* __restrict__ protos,
                const float* __restrict__ Wk, const float* __restrict__ bk,
                const float* __restrict__ Wv, const float* __restrict__ bv,
                char* __restrict__ wsb) {
    __shared__ float kf_s[P_][C_];
    __shared__ float vv_s[P_][C_];
    int tid = threadIdx.x;
    for (int idx = tid; idx < P_ * C_; idx += 1024) {
        int p = idx >> 7, c = idx & 127;
        const float* pr  = protos + p * C_;
        const float* wkr = Wk + (size_t)c * C_;
        const float* wvr = Wv + (size_t)c * C_;
        float ka = bk[c], va = bv[c];
        for (int j = 0; j < C_; j += 4) {
            float4 pv  = *(const float4*)(pr + j);
            float4 wk4 = *(const float4*)(wkr + j);
            float4 wv4 = *(const float4*)(wvr + j);
            ka = fmaf(pv.x, wk4.x, ka); ka = fmaf(pv.y, wk4.y, ka);
            ka = fmaf(pv.z, wk4.z, ka); ka = fmaf(pv.w, wk4.w, ka);
            va = fmaf(pv.x, wv4.x, va); va = fmaf(pv.y, wv4.y, va);
            va = fmaf(pv.z, wv4.z, va); va = fmaf(pv.w, wv4.w, va);
        }
        kf_s[p][c] = ka > 0.f ? ka + 1.f : expf(ka);
        vv_s[p][c] = va * (1.f / P_);
    }
    __syncthreads();
    short* kvt = (short*)(wsb + WS_KVT);
    float* ks  = (float*)(wsb + WS_KSUM);
    for (int idx = tid; idx < 4096; idx += 1024) {
        int col = idx >> 5, d = idx & 31;
        int h = col >> 5;
        float acc = 0.f;
        for (int p = 0; p < P_; ++p)
            acc = fmaf(kf_s[p][h * 32 + d], vv_s[p][col], acc);
        kvt[col * 32 + d] = f2b(acc);
    }
    if (tid < C_) {
        float acc = 0.f;
        for (int p = 0; p < P_; ++p) acc += kf_s[p][tid];
        ks[tid] = acc;
    }
}

// ---------------------------------------------------------------------------
// prep 2: weight conversion fp32 -> bf16 (Wq x-part, W1, W2)
// ---------------------------------------------------------------------------
__global__ __launch_bounds__(256)
void prep_conv(const float* __restrict__ Wq, const float* __restrict__ W1,
               const float* __restrict__ W2, char* __restrict__ wsb) {
    int idx = blockIdx.x * 256 + threadIdx.x;   // 576*256 = 147456 exact
    short* wqx = (short*)(wsb + WS_WQX);
    short* w1b = (short*)(wsb + WS_W1);
    short* w2b = (short*)(wsb + WS_W2);
    if (idx < 16384) {
        int c = idx >> 7, k = idx & 127;
        wqx[idx] = f2b(Wq[(size_t)c * 256 + k]);
    } else if (idx < 81920) {
        int i = idx - 16384;
        w1b[i] = f2b(W1[i]);
    } else {
        int i = idx - 81920;
        w2b[i] = f2b(W2[i]);
    }
}

// ---------------------------------------------------------------------------
// prep 3: qg[bt][c] = bq[c] + sum_g guid[bt][g] * Wq[c][128+g]
// ---------------------------------------------------------------------------
__global__ __launch_bounds__(128)
void prep_qg(const float* __restrict__ guid, const float* __restrict__ Wq,
             const float* __restrict__ bq, char* __restrict__ wsb) {
    __shared__ float gr[128];
    int bt = blockIdx.x, tid = threadIdx.x;
    gr[tid] = guid[(size_t)bt * 128 + tid];
    __syncthreads();
    const float* wr = Wq + (size_t)tid * 256 + 128;
    float acc = bq[tid];
    for (int g = 0; g < 128; g += 4) {
        float4 w4 = *(const float4*)(wr + g);
        acc = fmaf(gr[g],     w4.x, acc);
        acc = fmaf(gr[g + 1], w4.y, acc);
        acc = fmaf(gr[g + 2], w4.z, acc);
        acc = fmaf(gr[g + 3], w4.w, acc);
    }
    float* qg = (float*)(wsb + WS_QG);
    qg[(size_t)bt * 128 + tid] = acc;
}

// ---------------------------------------------------------------------------
// main: 64 tokens per block, 4 waves; wave w owns out-features [32w, 32w+32)
// ---------------------------------------------------------------------------
__global__ __launch_bounds__(256)
void cat_main(const float* __restrict__ x,
              const float* __restrict__ ln1_g, const float* __restrict__ ln1_b,
              const float* __restrict__ ln2_g, const float* __restrict__ ln2_b,
              const float* __restrict__ b1, const float* __restrict__ b2,
              const char* __restrict__ wsb, float* __restrict__ out) {
    __shared__ short bufA[TOK * C_];   // xt -> qf -> y       (bf16, swizzled)
    __shared__ short bufB[TOK * C_];   // o1 -> h chunks      (bf16, swizzled)
    __shared__ float qgs[C_], ksm[C_], lg1[C_], lb1[C_], lg2[C_], lb2[C_];
    __shared__ float mu1[TOK], rs1[TOK];

    const short* kvt   = (const short*)(wsb + WS_KVT);
    const float* ksumg = (const float*)(wsb + WS_KSUM);
    const short* wqx   = (const short*)(wsb + WS_WQX);
    const short* w1b   = (const short*)(wsb + WS_W1);
    const short* w2b   = (const short*)(wsb + WS_W2);
    const float* qg_g  = (const float*)(wsb + WS_QG);

    const int tid = threadIdx.x;
    const int w = tid >> 6, l = tid & 63;
    const int lr = l & 15, lg = l >> 4;
    const int t = blockIdx.y, b = blockIdx.z;
    const int bt = b * T_ + t;
    const int hw0 = blockIdx.x * TOK;
    const size_t xbase = (size_t)bt * C_ * HW_ + hw0;

    // ---- stage x -> bufA (token-major bf16, swizzled); coalesced reads ----
    {
        int c = tid >> 1, half = tid & 1;
        const float* src = x + xbase + (size_t)c * HW_ + half * 32;
        float v[32];
        #pragma unroll
        for (int i = 0; i < 8; ++i) {
            float4 f = *(const float4*)(src + i * 4);
            v[i * 4] = f.x; v[i * 4 + 1] = f.y; v[i * 4 + 2] = f.z; v[i * 4 + 3] = f.w;
        }
        #pragma unroll
        for (int i = 0; i < 32; ++i)
            bufA[swz(half * 32 + i, c)] = f2b(v[i]);
    }
    if (tid < C_) {
        qgs[tid] = qg_g[(size_t)bt * C_ + tid];
        ksm[tid] = ksumg[tid];
        lg1[tid] = ln1_g[tid]; lb1[tid] = ln1_b[tid];
        lg2[tid] = ln2_g[tid]; lb2[tid] = ln2_b[tid];
    }
    __syncthreads();

    // ---- LN1 stats (4 threads per token, vectorized swizzled reads) ----
    {
        int tok = tid >> 2, q = tid & 3;
        float s = 0.f, s2 = 0.f;
        #pragma unroll
        for (int j = 0; j < 4; ++j) {
            s16x8 v8 = *(const s16x8*)&bufA[swz(tok, q * 32 + j * 8)];
            #pragma unroll
            for (int e = 0; e < 8; ++e) {
                float v = b2f(v8[e]); s += v; s2 = fmaf(v, v, s2);
            }
        }
        s += __shfl_xor(s, 1); s2 += __shfl_xor(s2, 1);
        s += __shfl_xor(s, 2); s2 += __shfl_xor(s2, 2);
        if (q == 0) {
            float mu = s * (1.f / C_);
            mu1[tok] = mu;
            rs1[tok] = rsqrtf(s2 * (1.f / C_) - mu * mu + EPS_LN);
        }
    }
    __syncthreads();

    // ---- Q projection: D[tok][col], A = xt, B = Wq rows ----
    f32x4 qacc[4][2];
    #pragma unroll
    for (int mt = 0; mt < 4; ++mt)
        #pragma unroll
        for (int nbl = 0; nbl < 2; ++nbl)
            qacc[mt][nbl] = (f32x4){0.f, 0.f, 0.f, 0.f};
    #pragma unroll
    for (int kc = 0; kc < 4; ++kc) {
        bf16x8 af[4];
        #pragma unroll
        for (int mt = 0; mt < 4; ++mt)
            af[mt] = *(const bf16x8*)&bufA[swz(mt * 16 + lr, kc * 32 + lg * 8)];
        #pragma unroll
        for (int nbl = 0; nbl < 2; ++nbl) {
            int col = w * 32 + nbl * 16 + lr;
            bf16x8 bf = *(const bf16x8*)&wqx[col * C_ + kc * 32 + lg * 8];
            #pragma unroll
            for (int mt = 0; mt < 4; ++mt)
                qacc[mt][nbl] = __builtin_amdgcn_mfma_f32_16x16x32_bf16(
                    af[mt], bf, qacc[mt][nbl], 0, 0, 0);
        }
    }
    // ---- LN1 values at D-frag positions (scalar bf16 reads of x) ----
    f32x4 ln1v[4][2];
    #pragma unroll
    for (int mt = 0; mt < 4; ++mt)
        #pragma unroll
        for (int nbl = 0; nbl < 2; ++nbl) {
            int col = w * 32 + nbl * 16 + lr;
            float g1 = lg1[col], bb = lb1[col];
            #pragma unroll
            for (int r = 0; r < 4; ++r) {
                int tok = mt * 16 + lg * 4 + r;
                float xv = b2f(bufA[swz(tok, col)]);
                ln1v[mt][nbl][r] = fmaf((xv - mu1[tok]) * rs1[tok], g1, bb);
            }
        }
    __syncthreads();   // everyone done reading xt

    // ---- qf = elu(q)+1, Z denominator (16-lane shuffle reduce), write qf ----
    float qfv[4][2][4];
    float zz[4][4];
    #pragma unroll
    for (int mt = 0; mt < 4; ++mt) {
        float dp0 = 0.f, dp1 = 0.f, dp2 = 0.f, dp3 = 0.f;
        #pragma unroll
        for (int nbl = 0; nbl < 2; ++nbl) {
            int col = w * 32 + nbl * 16 + lr;
            float ks = ksm[col], qg = qgs[col];
            #pragma unroll
            for (int r = 0; r < 4; ++r) {
                float qv = qacc[mt][nbl][r] + qg;
                float f = qv > 0.f ? qv + 1.f : expf(qv);
                qfv[mt][nbl][r] = f;
                if (r == 0) dp0 = fmaf(f, ks, dp0);
                if (r == 1) dp1 = fmaf(f, ks, dp1);
                if (r == 2) dp2 = fmaf(f, ks, dp2);
                if (r == 3) dp3 = fmaf(f, ks, dp3);
            }
        }
        float dd[4] = {dp0, dp1, dp2, dp3};
        #pragma unroll
        for (int r = 0; r < 4; ++r) {
            float d = dd[r];
            d += __shfl_xor(d, 1); d += __shfl_xor(d, 2);
            d += __shfl_xor(d, 4); d += __shfl_xor(d, 8);
            zz[mt][r] = (float)P_ / (d + EPS_ATTN);
        }
    }
    #pragma unroll
    for (int mt = 0; mt < 4; ++mt)
        #pragma unroll
        for (int nbl = 0; nbl < 2; ++nbl)
            #pragma unroll
            for (int r = 0; r < 4; ++r)
                bufA[swz(mt * 16 + lg * 4 + r, w * 32 + nbl * 16 + lr)] =
                    f2b(qfv[mt][nbl][r]);
    __syncthreads();

    // ---- attention: block-diagonal KV, one k-chunk (head w) per wave ----
    f32x4 aacc[4][2];
    #pragma unroll
    for (int mt = 0; mt < 4; ++mt)
        #pragma unroll
        for (int nbl = 0; nbl < 2; ++nbl)
            aacc[mt][nbl] = (f32x4){0.f, 0.f, 0.f, 0.f};
    {
        bf16x8 af[4];
        #pragma unroll
        for (int mt = 0; mt < 4; ++mt)
            af[mt] = *(const bf16x8*)&bufA[swz(mt * 16 + lr, w * 32 + lg * 8)];
        #pragma unroll
        for (int nbl = 0; nbl < 2; ++nbl) {
            int col = w * 32 + nbl * 16 + lr;
            bf16x8 bf = *(const bf16x8*)&kvt[col * 32 + lg * 8];
            #pragma unroll
            for (int mt = 0; mt < 4; ++mt)
                aacc[mt][nbl] = __builtin_amdgcn_mfma_f32_16x16x32_bf16(
                    af[mt], bf, aacc[mt][nbl], 0, 0, 0);
        }
    }
    // ---- o1 = attn*Z + LN1(x); stash bf16 copy for LN2 stats ----
    f32x4 o1[4][2];
    #pragma unroll
    for (int mt = 0; mt < 4; ++mt)
        #pragma unroll
        for (int nbl = 0; nbl < 2; ++nbl)
            #pragma unroll
            for (int r = 0; r < 4; ++r)
                o1[mt][nbl][r] = fmaf(aacc[mt][nbl][r], zz[mt][r], ln1v[mt][nbl][r]);
    #pragma unroll
    for (int mt = 0; mt < 4; ++mt)
        #pragma unroll
        for (int nbl = 0; nbl < 2; ++nbl)
            #pragma unroll
            for (int r = 0; r < 4; ++r)
                bufB[swz(mt * 16 + lg * 4 + r, w * 32 + nbl * 16 + lr)] =
                    f2b(o1[mt][nbl][r]);
    __syncthreads();

    // ---- LN2 (single pass: stats via shuffles, write y bf16 to bufA) ----
    {
        int tok = tid >> 2, q = tid & 3;
        float vv[32];
        float s = 0.f, s2 = 0.f;
        #pragma unroll
        for (int j = 0; j < 4; ++j) {
            s16x8 v8 = *(const s16x8*)&bufB[swz(tok, q * 32 + j * 8)];
            #pragma unroll
            for (int e = 0; e < 8; ++e) {
                float v = b2f(v8[e]); vv[j * 8 + e] = v;
                s += v; s2 = fmaf(v, v, s2);
            }
        }
        s += __shfl_xor(s, 1); s2 += __shfl_xor(s2, 1);
        s += __shfl_xor(s, 2); s2 += __shfl_xor(s2, 2);
        float mu = s * (1.f / C_);
        float rs = rsqrtf(s2 * (1.f / C_) - mu * mu + EPS_LN);
        #pragma unroll
        for (int j = 0; j < 4; ++j) {
            s16x8 o;
            #pragma unroll
            for (int e = 0; e < 8; ++e) {
                int col = q * 32 + j * 8 + e;
                o[e] = f2b(fmaf((vv[j * 8 + e] - mu) * rs, lg2[col], lb2[col]));
            }
            *(s16x8*)&bufA[swz(tok, q * 32 + j * 8)] = o;
        }
    }
    __syncthreads();

    // ---- FFN: 4 chunks of 128 hidden; FFN1 -> GELU -> bufB -> FFN2 ----
    f32x4 facc[4][2];
    #pragma unroll
    for (int mt = 0; mt < 4; ++mt)
        #pragma unroll
        for (int nbl = 0; nbl < 2; ++nbl)
            facc[mt][nbl] = (f32x4){0.f, 0.f, 0.f, 0.f};

    for (int ch = 0; ch < 4; ++ch) {
        const int ff0 = ch * 128;
        f32x4 hacc[4][2];
        #pragma unroll
        for (int mt = 0; mt < 4; ++mt)
            #pragma unroll
            for (int nbl = 0; nbl < 2; ++nbl)
                hacc[mt][nbl] = (f32x4){0.f, 0.f, 0.f, 0.f};
        #pragma unroll
        for (int kc = 0; kc < 4; ++kc) {
            bf16x8 af[4];
            #pragma unroll
            for (int mt = 0; mt < 4; ++mt)
                af[mt] = *(const bf16x8*)&bufA[swz(mt * 16 + lr, kc * 32 + lg * 8)];
            #pragma unroll
            for (int nbl = 0; nbl < 2; ++nbl) {
                int row = ff0 + w * 32 + nbl * 16 + lr;
                bf16x8 bf = *(const bf16x8*)&w1b[row * C_ + kc * 32 + lg * 8];
                #pragma unroll
                for (int mt = 0; mt < 4; ++mt)
                    hacc[mt][nbl] = __builtin_amdgcn_mfma_f32_16x16x32_bf16(
                        af[mt], bf, hacc[mt][nbl], 0, 0, 0);
            }
        }
        // bias + exact GELU -> bufB
        #pragma unroll
        for (int nbl = 0; nbl < 2; ++nbl) {
            int ffc = ff0 + w * 32 + nbl * 16 + lr;
            float bb = b1[ffc];
            #pragma unroll
            for (int mt = 0; mt < 4; ++mt)
                #pragma unroll
                for (int r = 0; r < 4; ++r) {
                    float v = hacc[mt][nbl][r] + bb;
                    float g = 0.5f * v * (1.f + erff(v * 0.70710678118654752f));
                    bufB[swz(mt * 16 + lg * 4 + r, w * 32 + nbl * 16 + lr)] = f2b(g);
                }
        }
        __syncthreads();
        // FFN2 partial accumulate
        #pragma unroll
        for (int kc = 0; kc < 4; ++kc) {
            bf16x8 af[4];
            #pragma unroll
            for (int mt = 0; mt < 4; ++mt)
                af[mt] = *(const bf16x8*)&bufB[swz(mt * 16 + lr, kc * 32 + lg * 8)];
            #pragma unroll
            for (int nbl = 0; nbl < 2; ++nbl) {
                int col = w * 32 + nbl * 16 + lr;
                bf16x8 bf = *(const bf16x8*)&w2b[col * FF_ + ff0 + kc * 32 + lg * 8];
                #pragma unroll
                for (int mt = 0; mt < 4; ++mt)
                    facc[mt][nbl] = __builtin_amdgcn_mfma_f32_16x16x32_bf16(
                        af[mt], bf, facc[mt][nbl], 0, 0, 0);
            }
        }
        __syncthreads();
    }

    // ---- epilogue: out = o1 + ffn + b2; float4 stores along tokens ----
    #pragma unroll
    for (int mt = 0; mt < 4; ++mt)
        #pragma unroll
        for (int nbl = 0; nbl < 2; ++nbl) {
            int col = w * 32 + nbl * 16 + lr;
            float bb = b2[col];
            float4 o;
            o.x = o1[mt][nbl][0] + facc[mt][nbl][0] + bb;
            o.y = o1[mt][nbl][1] + facc[mt][nbl][1] + bb;
            o.z = o1[mt][nbl][2] + facc[mt][nbl][2] + bb;
            o.w = o1[mt][nbl][3] + facc[mt][nbl][3] + bb;
            float* dst = out + (size_t)bt * C_ * HW_ + (size_t)col * HW_
                         + hw0 + mt * 16 + lg * 4;
            *(float4*)dst = o;
        }
}

extern "C" void kernel_launch(void* const* d_in, const int* in_sizes, int n_in,
                              void* d_out, int out_size, void* d_ws, size_t ws_size,
                              hipStream_t stream) {
    (void)in_sizes; (void)n_in; (void)out_size; (void)ws_size;
    const float* x      = (const float*)d_in[0];
    const float* guid   = (const float*)d_in[1];
    const float* protos = (const float*)d_in[2];
    const float* Wq     = (const float*)d_in[3];
    const float* bq     = (const float*)d_in[4];
    const float* Wk     = (const float*)d_in[5];
    const float* bk     = (const float*)d_in[6];
    const float* Wv     = (const float*)d_in[7];
    const float* bv     = (const float*)d_in[8];
    const float* ln1_g  = (const float*)d_in[9];
    const float* ln1_b  = (const float*)d_in[10];
    const float* ln2_g  = (const float*)d_in[11];
    const float* ln2_b  = (const float*)d_in[12];
    const float* W1     = (const float*)d_in[13];
    const float* b1     = (const float*)d_in[14];
    const float* W2     = (const float*)d_in[15];
    const float* b2     = (const float*)d_in[16];
    float* out = (float*)d_out;
    char* wsb  = (char*)d_ws;

    prep_proto<<<1, 1024, 0, stream>>>(protos, Wk, bk, Wv, bv, wsb);
    prep_conv<<<576, 256, 0, stream>>>(Wq, W1, W2, wsb);
    prep_qg<<<512, 128, 0, stream>>>(guid, Wq, bq, wsb);
    dim3 grid(HW_ / TOK, T_, B_);
    cat_main<<<grid, 256, 0, stream>>>(x, ln1_g, ln1_b, ln2_g, ln2_b,
                                       b1, b2, wsb, out);
}

// Round 3
// 436.185 us; speedup vs baseline: 3.1644x; 1.4761x over previous
//
#include <hip/hip_runtime.h>
#include <math.h>

#define B_ 4
#define T_ 128
#define C_ 128
#define HW_ 576
#define P_ 32
#define FF_ 512
#define EPS_ATTN 1e-6f
#define EPS_LN 1e-5f
#define TOK 64

typedef __bf16 bf16x8 __attribute__((ext_vector_type(8)));
typedef float f32x4 __attribute__((ext_vector_type(4)));
typedef short s16x8 __attribute__((ext_vector_type(8)));
typedef short s16x4 __attribute__((ext_vector_type(4)));

// ---- ws byte offsets (16B aligned) ----
#define WS_KVT   0        // bf16 [128][32] : kvt[col][d] = KV[col>>5][d][col&31]
#define WS_KSUM  8192     // f32  [128]
#define WS_WQX   8704     // bf16 [128][128]
#define WS_W1    41472    // bf16 [512][128]
#define WS_W2    172544   // bf16 [128][512]
#define WS_QG    303616   // f32  [512][128] : guidance projection + bq

__device__ __forceinline__ short f2b(float f) {
    unsigned u = __builtin_bit_cast(unsigned, f);
    u = (u + 0x7fffu + ((u >> 16) & 1u)) >> 16;
    return (short)u;
}
__device__ __forceinline__ float b2f(short s) {
    return __builtin_bit_cast(float, ((unsigned)(unsigned short)s) << 16);
}
// swizzled short-index into [64][128] bf16 tile: XOR 16B granule by (row&7)
__device__ __forceinline__ int swz(int row, int col) {
    return (row << 7) | (col ^ ((row & 7) << 3));
}

// ---------------------------------------------------------------------------
// single prep kernel: blocks 0..575 convert weights; 576..831 guidance proj
// (2 bt each); block 832 prototypes -> kvt + ksum.
// ---------------------------------------------------------------------------
__global__ __launch_bounds__(256)
void prep_all(const float* __restrict__ protos,
              const float* __restrict__ Wk, const float* __restrict__ bk,
              const float* __restrict__ Wv, const float* __restrict__ bv,
              const float* __restrict__ Wq, const float* __restrict__ W1,
              const float* __restrict__ W2, const float* __restrict__ guid,
              const float* __restrict__ bq, char* __restrict__ wsb) {
    __shared__ float smA[4096];
    __shared__ float smB[4096];
    const int bid = blockIdx.x, tid = threadIdx.x;
    if (bid < 576) {
        int idx = bid * 256 + tid;           // 147456 total
        short* wqx = (short*)(wsb + WS_WQX);
        short* w1b = (short*)(wsb + WS_W1);
        short* w2b = (short*)(wsb + WS_W2);
        if (idx < 16384) {
            int c = idx >> 7, k = idx & 127;
            wqx[idx] = f2b(Wq[(size_t)c * 256 + k]);
        } else if (idx < 81920) {
            int i = idx - 16384;
            w1b[i] = f2b(W1[i]);
        } else {
            int i = idx - 81920;
            w2b[i] = f2b(W2[i]);
        }
    } else if (bid < 832) {
        int bt = (bid - 576) * 2 + (tid >> 7);
        int f = tid & 127;
        smA[tid] = guid[(size_t)bt * 128 + f];
        __syncthreads();
        const float* wr = Wq + (size_t)f * 256 + 128;
        const float* gg = &smA[(tid >> 7) * 128];
        float acc = bq[f];
        #pragma unroll
        for (int g = 0; g < 128; g += 4) {
            float4 w4 = *(const float4*)(wr + g);
            acc = fmaf(gg[g],     w4.x, acc);
            acc = fmaf(gg[g + 1], w4.y, acc);
            acc = fmaf(gg[g + 2], w4.z, acc);
            acc = fmaf(gg[g + 3], w4.w, acc);
        }
        ((float*)(wsb + WS_QG))[(size_t)bt * 128 + f] = acc;
    } else {
        // prototypes
        for (int idx = tid; idx < P_ * C_; idx += 256) {
            int p = idx >> 7, c = idx & 127;
            const float* pr  = protos + p * C_;
            const float* wkr = Wk + (size_t)c * C_;
            const float* wvr = Wv + (size_t)c * C_;
            float ka = bk[c], va = bv[c];
            for (int j = 0; j < C_; j += 4) {
                float4 pv  = *(const float4*)(pr + j);
                float4 wk4 = *(const float4*)(wkr + j);
                float4 wv4 = *(const float4*)(wvr + j);
                ka = fmaf(pv.x, wk4.x, ka); ka = fmaf(pv.y, wk4.y, ka);
                ka = fmaf(pv.z, wk4.z, ka); ka = fmaf(pv.w, wk4.w, ka);
                va = fmaf(pv.x, wv4.x, va); va = fmaf(pv.y, wv4.y, va);
                va = fmaf(pv.z, wv4.z, va); va = fmaf(pv.w, wv4.w, va);
            }
            smA[idx] = ka > 0.f ? ka + 1.f : expf(ka);   // kf
            smB[idx] = va * (1.f / P_);                  // vv
        }
        __syncthreads();
        short* kvt = (short*)(wsb + WS_KVT);
        float* ks  = (float*)(wsb + WS_KSUM);
        for (int idx = tid; idx < 4096; idx += 256) {
            int col = idx >> 5, d = idx & 31, h = col >> 5;
            float acc = 0.f;
            for (int p = 0; p < P_; ++p)
                acc = fmaf(smA[p * C_ + h * 32 + d], smB[p * C_ + col], acc);
            kvt[idx] = f2b(acc);
        }
        if (tid < C_) {
            float acc = 0.f;
            for (int p = 0; p < P_; ++p) acc += smA[p * C_ + tid];
            ks[tid] = acc;
        }
    }
}

// ---------------------------------------------------------------------------
// main: 64 tokens/block, 4 waves; wave w owns features [32w, 32w+32).
// All MFMAs swapped: D'[feat][tok] = W(A) x act(B); lane holds 4 consecutive
// feats x 1 token -> b64 LDS writes, b128 reads, lane-local Z / LN2.
// ---------------------------------------------------------------------------
__global__ __launch_bounds__(256, 4)
void cat_main(const float* __restrict__ x,
              const float* __restrict__ ln1_g, const float* __restrict__ ln1_b,
              const float* __restrict__ ln2_g, const float* __restrict__ ln2_b,
              const float* __restrict__ b1, const float* __restrict__ b2,
              const char* __restrict__ wsb, float* __restrict__ out) {
    __shared__ short bufA[TOK * C_];   // x -> y
    __shared__ short bufB[TOK * C_];   // qf -> h chunks
    __shared__ float mu1[TOK], rs1[TOK];
    __shared__ float zp[TOK][4];
    __shared__ float lnS[TOK][4], lnS2[TOK][4];

    const short* kvt  = (const short*)(wsb + WS_KVT);
    const float* ksum = (const float*)(wsb + WS_KSUM);
    const short* wqx  = (const short*)(wsb + WS_WQX);
    const short* w1b  = (const short*)(wsb + WS_W1);
    const short* w2b  = (const short*)(wsb + WS_W2);
    const float* qg_g = (const float*)(wsb + WS_QG);

    const int tid = threadIdx.x;
    const int w = tid >> 6, l = tid & 63;
    const int lr = l & 15, lg = l >> 4;
    const int bt = blockIdx.z * T_ + blockIdx.y;
    const int hw0 = blockIdx.x * TOK;
    const int cb0 = w * 32 + lg * 4;        // feature base (nbl=0)

    // ---- stage x -> bufA (token-major bf16, swizzled) ----
    {
        int c = tid >> 1, half = tid & 1;
        const float* src = x + ((size_t)bt * C_ + c) * HW_ + hw0 + half * 32;
        #pragma unroll
        for (int i = 0; i < 8; ++i) {
            float4 f = *(const float4*)(src + i * 4);
            bufA[swz(half * 32 + i * 4 + 0, c)] = f2b(f.x);
            bufA[swz(half * 32 + i * 4 + 1, c)] = f2b(f.y);
            bufA[swz(half * 32 + i * 4 + 2, c)] = f2b(f.z);
            bufA[swz(half * 32 + i * 4 + 3, c)] = f2b(f.w);
        }
    }
    __syncthreads();

    // ---- LN1 stats (4 threads/token, b128 reads) ----
    {
        int tok = tid >> 2, q = tid & 3;
        float s = 0.f, s2 = 0.f;
        #pragma unroll
        for (int j = 0; j < 4; ++j) {
            s16x8 v8 = *(const s16x8*)&bufA[swz(tok, q * 32 + j * 8)];
            #pragma unroll
            for (int e = 0; e < 8; ++e) {
                float v = b2f(v8[e]); s += v; s2 = fmaf(v, v, s2);
            }
        }
        s += __shfl_xor(s, 1); s2 += __shfl_xor(s2, 1);
        s += __shfl_xor(s, 2); s2 += __shfl_xor(s2, 2);
        if (q == 0) {
            float mu = s * (1.f / C_);
            mu1[tok] = mu;
            rs1[tok] = rsqrtf(s2 * (1.f / C_) - mu * mu + EPS_LN);
        }
    }

    // ---- Q projection: D'[feat][tok] = Wq(A) x x(B) ----
    f32x4 qacc[2][4];
    #pragma unroll
    for (int nbl = 0; nbl < 2; ++nbl)
        #pragma unroll
        for (int mt = 0; mt < 4; ++mt)
            qacc[nbl][mt] = (f32x4){0.f, 0.f, 0.f, 0.f};
    #pragma unroll
    for (int kc = 0; kc < 4; ++kc) {
        bf16x8 bx[4];
        #pragma unroll
        for (int mt = 0; mt < 4; ++mt)
            bx[mt] = *(const bf16x8*)&bufA[swz(mt * 16 + lr, kc * 32 + lg * 8)];
        #pragma unroll
        for (int nbl = 0; nbl < 2; ++nbl) {
            bf16x8 aw = *(const bf16x8*)&wqx[(w * 32 + nbl * 16 + lr) * C_ + kc * 32 + lg * 8];
            #pragma unroll
            for (int mt = 0; mt < 4; ++mt)
                qacc[nbl][mt] = __builtin_amdgcn_mfma_f32_16x16x32_bf16(
                    aw, bx[mt], qacc[nbl][mt], 0, 0, 0);
        }
    }

    // ---- elu(q+qg)+1 -> qf (b64 writes to bufB) + Z partials ----
    float dp[4] = {0.f, 0.f, 0.f, 0.f};
    #pragma unroll
    for (int nbl = 0; nbl < 2; ++nbl) {
        int cb = cb0 + nbl * 16;
        f32x4 qg4 = *(const f32x4*)&qg_g[(size_t)bt * C_ + cb];
        f32x4 ks4 = *(const f32x4*)&ksum[cb];
        #pragma unroll
        for (int mt = 0; mt < 4; ++mt) {
            s16x4 pk;
            #pragma unroll
            for (int r = 0; r < 4; ++r) {
                float qv = qacc[nbl][mt][r] + qg4[r];
                float f = qv > 0.f ? qv + 1.f : expf(qv);
                dp[mt] = fmaf(f, ks4[r], dp[mt]);
                pk[r] = f2b(f);
            }
            *(s16x4*)&bufB[swz(mt * 16 + lr, cb)] = pk;
        }
    }
    #pragma unroll
    for (int mt = 0; mt < 4; ++mt) {
        dp[mt] += __shfl_xor(dp[mt], 16);
        dp[mt] += __shfl_xor(dp[mt], 32);
    }
    if (lg == 0) {
        #pragma unroll
        for (int mt = 0; mt < 4; ++mt) zp[mt * 16 + lr][w] = dp[mt];
    }
    __syncthreads();

    // ---- attention: D'[feat][tok] = kvt(A) x qf(B), K=32 (head w) ----
    f32x4 aacc[2][4];
    #pragma unroll
    for (int nbl = 0; nbl < 2; ++nbl)
        #pragma unroll
        for (int mt = 0; mt < 4; ++mt)
            aacc[nbl][mt] = (f32x4){0.f, 0.f, 0.f, 0.f};
    {
        bf16x8 bq_[4];
        #pragma unroll
        for (int mt = 0; mt < 4; ++mt)
            bq_[mt] = *(const bf16x8*)&bufB[swz(mt * 16 + lr, w * 32 + lg * 8)];
        #pragma unroll
        for (int nbl = 0; nbl < 2; ++nbl) {
            bf16x8 aw = *(const bf16x8*)&kvt[(w * 32 + nbl * 16 + lr) * 32 + lg * 8];
            #pragma unroll
            for (int mt = 0; mt < 4; ++mt)
                aacc[nbl][mt] = __builtin_amdgcn_mfma_f32_16x16x32_bf16(
                    aw, bq_[mt], aacc[nbl][mt], 0, 0, 0);
        }
    }
    float zv[4];
    #pragma unroll
    for (int mt = 0; mt < 4; ++mt) {
        f32x4 z4 = *(const f32x4*)&zp[mt * 16 + lr][0];
        zv[mt] = (float)P_ / (z4[0] + z4[1] + z4[2] + z4[3] + EPS_ATTN);
    }

    // ---- o1 = attn*Z + LN1(x); LN2 partials from registers ----
    f32x4 o1[2][4];
    #pragma unroll
    for (int nbl = 0; nbl < 2; ++nbl) {
        int cb = cb0 + nbl * 16;
        f32x4 g1 = *(const f32x4*)&ln1_g[cb];
        f32x4 bb1 = *(const f32x4*)&ln1_b[cb];
        #pragma unroll
        for (int mt = 0; mt < 4; ++mt) {
            int tok = mt * 16 + lr;
            s16x4 xv = *(const s16x4*)&bufA[swz(tok, cb)];
            float mu = mu1[tok], rs = rs1[tok];
            #pragma unroll
            for (int r = 0; r < 4; ++r) {
                float ln1 = fmaf((b2f(xv[r]) - mu) * rs, g1[r], bb1[r]);
                o1[nbl][mt][r] = fmaf(aacc[nbl][mt][r], zv[mt], ln1);
            }
        }
    }
    #pragma unroll
    for (int mt = 0; mt < 4; ++mt) {
        float s = 0.f, s2 = 0.f;
        #pragma unroll
        for (int nbl = 0; nbl < 2; ++nbl)
            #pragma unroll
            for (int r = 0; r < 4; ++r) {
                float v = o1[nbl][mt][r];
                s += v; s2 = fmaf(v, v, s2);
            }
        s += __shfl_xor(s, 16); s2 += __shfl_xor(s2, 16);
        s += __shfl_xor(s, 32); s2 += __shfl_xor(s2, 32);
        if (lg == 0) { lnS[mt * 16 + lr][w] = s; lnS2[mt * 16 + lr][w] = s2; }
    }
    __syncthreads();

    // ---- y = LN2(o1) -> bufA (b64 writes) ----
    float mu2[4], rs2v[4];
    #pragma unroll
    for (int mt = 0; mt < 4; ++mt) {
        f32x4 sv = *(const f32x4*)&lnS[mt * 16 + lr][0];
        f32x4 s2v = *(const f32x4*)&lnS2[mt * 16 + lr][0];
        float ss = sv[0] + sv[1] + sv[2] + sv[3];
        float ss2 = s2v[0] + s2v[1] + s2v[2] + s2v[3];
        float mu = ss * (1.f / C_);
        mu2[mt] = mu;
        rs2v[mt] = rsqrtf(ss2 * (1.f / C_) - mu * mu + EPS_LN);
    }
    #pragma unroll
    for (int nbl = 0; nbl < 2; ++nbl) {
        int cb = cb0 + nbl * 16;
        f32x4 g2 = *(const f32x4*)&ln2_g[cb];
        f32x4 bb2 = *(const f32x4*)&ln2_b[cb];
        #pragma unroll
        for (int mt = 0; mt < 4; ++mt) {
            s16x4 pk;
            #pragma unroll
            for (int r = 0; r < 4; ++r)
                pk[r] = f2b(fmaf((o1[nbl][mt][r] - mu2[mt]) * rs2v[mt], g2[r], bb2[r]));
            *(s16x4*)&bufA[swz(mt * 16 + lr, cb)] = pk;
        }
    }
    __syncthreads();

    // ---- FFN: facc starts at o1 + b2 (MFMA C-accumulate) ----
    f32x4 facc[2][4];
    #pragma unroll
    for (int nbl = 0; nbl < 2; ++nbl) {
        f32x4 bv2 = *(const f32x4*)&b2[cb0 + nbl * 16];
        #pragma unroll
        for (int mt = 0; mt < 4; ++mt)
            #pragma unroll
            for (int r = 0; r < 4; ++r)
                facc[nbl][mt][r] = o1[nbl][mt][r] + bv2[r];
    }
    for (int ch = 0; ch < 4; ++ch) {
        if (ch) __syncthreads();
        f32x4 hacc[2][4];
        #pragma unroll
        for (int nbl = 0; nbl < 2; ++nbl)
            #pragma unroll
            for (int mt = 0; mt < 4; ++mt)
                hacc[nbl][mt] = (f32x4){0.f, 0.f, 0.f, 0.f};
        #pragma unroll
        for (int kc = 0; kc < 4; ++kc) {
            bf16x8 by[4];
            #pragma unroll
            for (int mt = 0; mt < 4; ++mt)
                by[mt] = *(const bf16x8*)&bufA[swz(mt * 16 + lr, kc * 32 + lg * 8)];
            #pragma unroll
            for (int nbl = 0; nbl < 2; ++nbl) {
                bf16x8 aw = *(const bf16x8*)&w1b[(ch * 128 + w * 32 + nbl * 16 + lr) * C_ + kc * 32 + lg * 8];
                #pragma unroll
                for (int mt = 0; mt < 4; ++mt)
                    hacc[nbl][mt] = __builtin_amdgcn_mfma_f32_16x16x32_bf16(
                        aw, by[mt], hacc[nbl][mt], 0, 0, 0);
            }
        }
        #pragma unroll
        for (int nbl = 0; nbl < 2; ++nbl) {
            int cb = cb0 + nbl * 16;
            f32x4 bb = *(const f32x4*)&b1[ch * 128 + cb];
            #pragma unroll
            for (int mt = 0; mt < 4; ++mt) {
                s16x4 pk;
                #pragma unroll
                for (int r = 0; r < 4; ++r) {
                    float v = hacc[nbl][mt][r] + bb[r];
                    pk[r] = f2b(0.5f * v * (1.f + erff(v * 0.70710678118654752f)));
                }
                *(s16x4*)&bufB[swz(mt * 16 + lr, cb)] = pk;
            }
        }
        __syncthreads();
        #pragma unroll
        for (int kc = 0; kc < 4; ++kc) {
            bf16x8 bh[4];
            #pragma unroll
            for (int mt = 0; mt < 4; ++mt)
                bh[mt] = *(const bf16x8*)&bufB[swz(mt * 16 + lr, kc * 32 + lg * 8)];
            #pragma unroll
            for (int nbl = 0; nbl < 2; ++nbl) {
                bf16x8 aw = *(const bf16x8*)&w2b[(w * 32 + nbl * 16 + lr) * FF_ + ch * 128 + kc * 32 + lg * 8];
                #pragma unroll
                for (int mt = 0; mt < 4; ++mt)
                    facc[nbl][mt] = __builtin_amdgcn_mfma_f32_16x16x32_bf16(
                        aw, bh[mt], facc[nbl][mt], 0, 0, 0);
            }
        }
    }

    // ---- epilogue: facc already = o1 + ffn + b2 ----
    #pragma unroll
    for (int nbl = 0; nbl < 2; ++nbl) {
        int cb = cb0 + nbl * 16;
        #pragma unroll
        for (int mt = 0; mt < 4; ++mt) {
            int tok = mt * 16 + lr;
            float* dst = out + ((size_t)bt * C_ + cb) * HW_ + hw0 + tok;
            #pragma unroll
            for (int r = 0; r < 4; ++r)
                dst[(size_t)r * HW_] = facc[nbl][mt][r];
        }
    }
}

extern "C" void kernel_launch(void* const* d_in, const int* in_sizes, int n_in,
                              void* d_out, int out_size, void* d_ws, size_t ws_size,
                              hipStream_t stream) {
    (void)in_sizes; (void)n_in; (void)out_size; (void)ws_size;
    const float* x      = (const float*)d_in[0];
    const float* guid   = (const float*)d_in[1];
    const float* protos = (const float*)d_in[2];
    const float* Wq     = (const float*)d_in[3];
    const float* bq     = (const float*)d_in[4];
    const float* Wk     = (const float*)d_in[5];
    const float* bk     = (const float*)d_in[6];
    const float* Wv     = (const float*)d_in[7];
    const float* bv     = (const float*)d_in[8];
    const float* ln1_g  = (const float*)d_in[9];
    const float* ln1_b  = (const float*)d_in[10];
    const float* ln2_g  = (const float*)d_in[11];
    const float* ln2_b  = (const float*)d_in[12];
    const float* W1     = (const float*)d_in[13];
    const float* b1     = (const float*)d_in[14];
    const float* W2     = (const float*)d_in[15];
    const float* b2     = (const float*)d_in[16];
    float* out = (float*)d_out;
    char* wsb  = (char*)d_ws;

    prep_all<<<833, 256, 0, stream>>>(protos, Wk, bk, Wv, bv, Wq, W1, W2,
                                      guid, bq, wsb);
    dim3 grid(HW_ / TOK, T_, B_);
    cat_main<<<grid, 256, 0, stream>>>(x, ln1_g, ln1_b, ln2_g, ln2_b,
                                       b1, b2, wsb, out);
}

// Round 4
// 375.964 us; speedup vs baseline: 3.6713x; 1.1602x over previous
//
#include <hip/hip_runtime.h>
#include <math.h>

#define B_ 4
#define T_ 128
#define C_ 128
#define HW_ 576
#define P_ 32
#define FF_ 512
#define EPS_ATTN 1e-6f
#define EPS_LN 1e-5f
#define TOK 64

typedef __bf16 bf16x8 __attribute__((ext_vector_type(8)));
typedef float f32x4 __attribute__((ext_vector_type(4)));
typedef short s16x8 __attribute__((ext_vector_type(8)));
typedef short s16x4 __attribute__((ext_vector_type(4)));

// ---- ws byte offsets (16B aligned) ----
#define WS_KVT   0        // bf16 [128][32] : kvt[col][d] = KV[col>>5][d][col&31]
#define WS_KSUM  8192     // f32  [128]
#define WS_WQX   8704     // bf16 [128][128]
#define WS_W1    41472    // bf16 [512][128]
#define WS_W2    172544   // bf16 [128][512]
#define WS_QG    303616   // f32  [512][128] : guidance projection + bq

__device__ __forceinline__ short f2b(float f) {
    unsigned u = __builtin_bit_cast(unsigned, f);
    u = (u + 0x7fffu + ((u >> 16) & 1u)) >> 16;
    return (short)u;
}
__device__ __forceinline__ float b2f(short s) {
    return __builtin_bit_cast(float, ((unsigned)(unsigned short)s) << 16);
}
// swizzled short-index into [64][128] bf16 tile: XOR 16B granule by (row&7)
__device__ __forceinline__ int swz(int row, int col) {
    return (row << 7) | (col ^ ((row & 7) << 3));
}
// tanh-form GELU: |err| <= ~3e-3, below bf16 rounding of h
__device__ __forceinline__ float gelu_f(float v) {
    float u = v * fmaf(v * v, 0.0356774081f, 0.7978845608f);
    float e = __expf(-2.f * fabsf(u));
    float t = copysignf((1.f - e) * __builtin_amdgcn_rcpf(1.f + e), u);
    return 0.5f * v * (1.f + t);
}

// ---------------------------------------------------------------------------
// prep: blocks 0..575 weight conversion; 576..831 guidance proj; 832 protos
// ---------------------------------------------------------------------------
__global__ __launch_bounds__(256)
void prep_all(const float* __restrict__ protos,
              const float* __restrict__ Wk, const float* __restrict__ bk,
              const float* __restrict__ Wv, const float* __restrict__ bv,
              const float* __restrict__ Wq, const float* __restrict__ W1,
              const float* __restrict__ W2, const float* __restrict__ guid,
              const float* __restrict__ bq, char* __restrict__ wsb) {
    __shared__ float smA[4096];
    __shared__ float smB[4096];
    const int bid = blockIdx.x, tid = threadIdx.x;
    if (bid < 576) {
        int idx = bid * 256 + tid;
        short* wqx = (short*)(wsb + WS_WQX);
        short* w1b = (short*)(wsb + WS_W1);
        short* w2b = (short*)(wsb + WS_W2);
        if (idx < 16384) {
            int c = idx >> 7, k = idx & 127;
            wqx[idx] = f2b(Wq[(size_t)c * 256 + k]);
        } else if (idx < 81920) {
            int i = idx - 16384;
            w1b[i] = f2b(W1[i]);
        } else {
            int i = idx - 81920;
            w2b[i] = f2b(W2[i]);
        }
    } else if (bid < 832) {
        int bt = (bid - 576) * 2 + (tid >> 7);
        int f = tid & 127;
        smA[tid] = guid[(size_t)bt * 128 + f];
        __syncthreads();
        const float* wr = Wq + (size_t)f * 256 + 128;
        const float* gg = &smA[(tid >> 7) * 128];
        float acc = bq[f];
        #pragma unroll
        for (int g = 0; g < 128; g += 4) {
            float4 w4 = *(const float4*)(wr + g);
            acc = fmaf(gg[g],     w4.x, acc);
            acc = fmaf(gg[g + 1], w4.y, acc);
            acc = fmaf(gg[g + 2], w4.z, acc);
            acc = fmaf(gg[g + 3], w4.w, acc);
        }
        ((float*)(wsb + WS_QG))[(size_t)bt * 128 + f] = acc;
    } else {
        for (int idx = tid; idx < P_ * C_; idx += 256) {
            int p = idx >> 7, c = idx & 127;
            const float* pr  = protos + p * C_;
            const float* wkr = Wk + (size_t)c * C_;
            const float* wvr = Wv + (size_t)c * C_;
            float ka = bk[c], va = bv[c];
            for (int j = 0; j < C_; j += 4) {
                float4 pv  = *(const float4*)(pr + j);
                float4 wk4 = *(const float4*)(wkr + j);
                float4 wv4 = *(const float4*)(wvr + j);
                ka = fmaf(pv.x, wk4.x, ka); ka = fmaf(pv.y, wk4.y, ka);
                ka = fmaf(pv.z, wk4.z, ka); ka = fmaf(pv.w, wk4.w, ka);
                va = fmaf(pv.x, wv4.x, va); va = fmaf(pv.y, wv4.y, va);
                va = fmaf(pv.z, wv4.z, va); va = fmaf(pv.w, wv4.w, va);
            }
            smA[idx] = ka > 0.f ? ka + 1.f : __expf(ka);
            smB[idx] = va * (1.f / P_);
        }
        __syncthreads();
        short* kvt = (short*)(wsb + WS_KVT);
        float* ks  = (float*)(wsb + WS_KSUM);
        for (int idx = tid; idx < 4096; idx += 256) {
            int col = idx >> 5, d = idx & 31, h = col >> 5;
            float acc = 0.f;
            for (int p = 0; p < P_; ++p)
                acc = fmaf(smA[p * C_ + h * 32 + d], smB[p * C_ + col], acc);
            kvt[idx] = f2b(acc);
        }
        if (tid < C_) {
            float acc = 0.f;
            for (int p = 0; p < P_; ++p) acc += smA[p * C_ + tid];
            ks[tid] = acc;
        }
    }
}

// ---------------------------------------------------------------------------
// main: 64 tokens/block, 8 waves of 64; wave w owns features [16w, 16w+16).
// Swapped MFMAs: D'[feat][tok] = W(A) x act(B).
//   A-frag row = w*16 + lr (feature), k = lg*8+e
//   B-frag     = act[tok = mt*16+lr][k = kc*32 + lg*8 ..]
//   D-frag     : feat = w*16 + lg*4 + r, tok = mt*16 + lr
// ---------------------------------------------------------------------------
__global__ __launch_bounds__(512, 8)
void cat_main(const float* __restrict__ x,
              const float* __restrict__ ln1_g, const float* __restrict__ ln1_b,
              const float* __restrict__ ln2_g, const float* __restrict__ ln2_b,
              const float* __restrict__ b1, const float* __restrict__ b2,
              const char* __restrict__ wsb, float* __restrict__ out) {
    __shared__ short bufA[TOK * C_];   // x -> y
    __shared__ short bufB[TOK * C_];   // qf -> h chunks
    __shared__ float mu1[TOK], rs1[TOK];
    __shared__ float zp[TOK][8];
    __shared__ float lnS[TOK][8], lnS2[TOK][8];

    const short* kvt  = (const short*)(wsb + WS_KVT);
    const float* ksum = (const float*)(wsb + WS_KSUM);
    const short* wqx  = (const short*)(wsb + WS_WQX);
    const short* w1b  = (const short*)(wsb + WS_W1);
    const short* w2b  = (const short*)(wsb + WS_W2);
    const float* qg_g = (const float*)(wsb + WS_QG);

    const int tid = threadIdx.x;
    const int w = tid >> 6, l = tid & 63;
    const int lr = l & 15, lg = l >> 4;
    const int bt = blockIdx.z * T_ + blockIdx.y;
    const int hw0 = blockIdx.x * TOK;
    const int frow = w * 16 + lr;          // A-operand feature row
    const int cb0 = w * 16 + lg * 4;       // D-frag feature base

    // ---- stage x -> bufA: 4-channel x 4-token register tile, b64 writes ----
    {
        int cb = tid >> 4, tg = tid & 15;   // cb: 4-chan block, tg: 4-tok group
        float4 v[4];
        #pragma unroll
        for (int i = 0; i < 4; ++i)
            v[i] = *(const float4*)(x + ((size_t)bt * C_ + cb * 4 + i) * HW_
                                    + hw0 + tg * 4);
        #pragma unroll
        for (int j = 0; j < 4; ++j) {
            s16x4 pk;
            pk[0] = f2b(((const float*)&v[0])[j]);
            pk[1] = f2b(((const float*)&v[1])[j]);
            pk[2] = f2b(((const float*)&v[2])[j]);
            pk[3] = f2b(((const float*)&v[3])[j]);
            *(s16x4*)&bufA[swz(tg * 4 + j, cb * 4)] = pk;
        }
    }
    __syncthreads();

    // ---- LN1 stats: 8 threads/token ----
    {
        int tok = tid >> 3, q = tid & 7;
        float s = 0.f, s2 = 0.f;
        #pragma unroll
        for (int j = 0; j < 2; ++j) {
            s16x8 v8 = *(const s16x8*)&bufA[swz(tok, q * 16 + j * 8)];
            #pragma unroll
            for (int e = 0; e < 8; ++e) {
                float v = b2f(v8[e]); s += v; s2 = fmaf(v, v, s2);
            }
        }
        s += __shfl_xor(s, 1); s2 += __shfl_xor(s2, 1);
        s += __shfl_xor(s, 2); s2 += __shfl_xor(s2, 2);
        s += __shfl_xor(s, 4); s2 += __shfl_xor(s2, 4);
        if (q == 0) {
            float mu = s * (1.f / C_);
            mu1[tok] = mu;
            rs1[tok] = rsqrtf(s2 * (1.f / C_) - mu * mu + EPS_LN);
        }
    }

    // ---- Q projection ----
    f32x4 qacc[4];
    #pragma unroll
    for (int mt = 0; mt < 4; ++mt) qacc[mt] = (f32x4){0.f, 0.f, 0.f, 0.f};
    #pragma unroll
    for (int kc = 0; kc < 4; ++kc) {
        bf16x8 aw = *(const bf16x8*)&wqx[frow * C_ + kc * 32 + lg * 8];
        #pragma unroll
        for (int mt = 0; mt < 4; ++mt) {
            bf16x8 bx = *(const bf16x8*)&bufA[swz(mt * 16 + lr, kc * 32 + lg * 8)];
            qacc[mt] = __builtin_amdgcn_mfma_f32_16x16x32_bf16(aw, bx, qacc[mt], 0, 0, 0);
        }
    }

    // ---- qf = elu(q+qg)+1 -> bufB (b64), Z partials ----
    {
        f32x4 qg4 = *(const f32x4*)&qg_g[(size_t)bt * C_ + cb0];
        f32x4 ks4 = *(const f32x4*)&ksum[cb0];
        #pragma unroll
        for (int mt = 0; mt < 4; ++mt) {
            float dp = 0.f;
            s16x4 pk;
            #pragma unroll
            for (int r = 0; r < 4; ++r) {
                float qv = qacc[mt][r] + qg4[r];
                float f = qv > 0.f ? qv + 1.f : __expf(qv);
                dp = fmaf(f, ks4[r], dp);
                pk[r] = f2b(f);
            }
            *(s16x4*)&bufB[swz(mt * 16 + lr, cb0)] = pk;
            dp += __shfl_xor(dp, 16);
            dp += __shfl_xor(dp, 32);
            if (lg == 0) zp[mt * 16 + lr][w] = dp;
        }
    }
    __syncthreads();

    // ---- attention: K=32 (head w>>1) ----
    f32x4 aacc[4];
    {
        const int h = w >> 1;
        bf16x8 aw = *(const bf16x8*)&kvt[frow * 32 + lg * 8];
        #pragma unroll
        for (int mt = 0; mt < 4; ++mt) {
            bf16x8 bq_ = *(const bf16x8*)&bufB[swz(mt * 16 + lr, h * 32 + lg * 8)];
            aacc[mt] = __builtin_amdgcn_mfma_f32_16x16x32_bf16(
                aw, bq_, (f32x4){0.f, 0.f, 0.f, 0.f}, 0, 0, 0);
        }
    }

    // ---- o1 = attn*Z + LN1(x); LN2 partials ----
    f32x4 o1[4];
    {
        f32x4 g1 = *(const f32x4*)&ln1_g[cb0];
        f32x4 bb1 = *(const f32x4*)&ln1_b[cb0];
        #pragma unroll
        for (int mt = 0; mt < 4; ++mt) {
            int tok = mt * 16 + lr;
            f32x4 za = *(const f32x4*)&zp[tok][0];
            f32x4 zb = *(const f32x4*)&zp[tok][4];
            float zv = (float)P_ /
                (za[0] + za[1] + za[2] + za[3] + zb[0] + zb[1] + zb[2] + zb[3] + EPS_ATTN);
            s16x4 xv = *(const s16x4*)&bufA[swz(tok, cb0)];
            float mu = mu1[tok], rs = rs1[tok];
            float s = 0.f, s2 = 0.f;
            #pragma unroll
            for (int r = 0; r < 4; ++r) {
                float ln1 = fmaf((b2f(xv[r]) - mu) * rs, g1[r], bb1[r]);
                float v = fmaf(aacc[mt][r], zv, ln1);
                o1[mt][r] = v;
                s += v; s2 = fmaf(v, v, s2);
            }
            s += __shfl_xor(s, 16); s2 += __shfl_xor(s2, 16);
            s += __shfl_xor(s, 32); s2 += __shfl_xor(s2, 32);
            if (lg == 0) { lnS[tok][w] = s; lnS2[tok][w] = s2; }
        }
    }
    __syncthreads();

    // ---- y = LN2(o1) -> bufA ----
    {
        f32x4 g2 = *(const f32x4*)&ln2_g[cb0];
        f32x4 bb2 = *(const f32x4*)&ln2_b[cb0];
        #pragma unroll
        for (int mt = 0; mt < 4; ++mt) {
            int tok = mt * 16 + lr;
            f32x4 sa = *(const f32x4*)&lnS[tok][0];
            f32x4 sb = *(const f32x4*)&lnS[tok][4];
            f32x4 pa = *(const f32x4*)&lnS2[tok][0];
            f32x4 pb = *(const f32x4*)&lnS2[tok][4];
            float ss = sa[0] + sa[1] + sa[2] + sa[3] + sb[0] + sb[1] + sb[2] + sb[3];
            float ss2 = pa[0] + pa[1] + pa[2] + pa[3] + pb[0] + pb[1] + pb[2] + pb[3];
            float mu = ss * (1.f / C_);
            float rs = rsqrtf(ss2 * (1.f / C_) - mu * mu + EPS_LN);
            s16x4 pk;
            #pragma unroll
            for (int r = 0; r < 4; ++r)
                pk[r] = f2b(fmaf((o1[mt][r] - mu) * rs, g2[r], bb2[r]));
            *(s16x4*)&bufA[swz(tok, cb0)] = pk;
        }
    }
    __syncthreads();

    // ---- FFN ----
    f32x4 facc[4];
    {
        f32x4 bv2 = *(const f32x4*)&b2[cb0];
        #pragma unroll
        for (int mt = 0; mt < 4; ++mt)
            #pragma unroll
            for (int r = 0; r < 4; ++r)
                facc[mt][r] = o1[mt][r] + bv2[r];
    }
    for (int ch = 0; ch < 4; ++ch) {
        f32x4 hacc[4];
        #pragma unroll
        for (int mt = 0; mt < 4; ++mt) hacc[mt] = (f32x4){0.f, 0.f, 0.f, 0.f};
        #pragma unroll
        for (int kc = 0; kc < 4; ++kc) {
            bf16x8 aw = *(const bf16x8*)&w1b[(ch * 128 + frow) * C_ + kc * 32 + lg * 8];
            #pragma unroll
            for (int mt = 0; mt < 4; ++mt) {
                bf16x8 by = *(const bf16x8*)&bufA[swz(mt * 16 + lr, kc * 32 + lg * 8)];
                hacc[mt] = __builtin_amdgcn_mfma_f32_16x16x32_bf16(aw, by, hacc[mt], 0, 0, 0);
            }
        }
        f32x4 bb = *(const f32x4*)&b1[ch * 128 + cb0];
        #pragma unroll
        for (int mt = 0; mt < 4; ++mt) {
            s16x4 pk;
            #pragma unroll
            for (int r = 0; r < 4; ++r)
                pk[r] = f2b(gelu_f(hacc[mt][r] + bb[r]));
            *(s16x4*)&bufB[swz(mt * 16 + lr, cb0)] = pk;
        }
        __syncthreads();
        #pragma unroll
        for (int kc = 0; kc < 4; ++kc) {
            bf16x8 aw = *(const bf16x8*)&w2b[frow * FF_ + ch * 128 + kc * 32 + lg * 8];
            #pragma unroll
            for (int mt = 0; mt < 4; ++mt) {
                bf16x8 bh = *(const bf16x8*)&bufB[swz(mt * 16 + lr, kc * 32 + lg * 8)];
                facc[mt] = __builtin_amdgcn_mfma_f32_16x16x32_bf16(aw, bh, facc[mt], 0, 0, 0);
            }
        }
        __syncthreads();
    }

    // ---- epilogue (facc = o1 + ffn + b2); 64B-segment coalesced stores ----
    #pragma unroll
    for (int mt = 0; mt < 4; ++mt) {
        int tok = mt * 16 + lr;
        #pragma unroll
        for (int r = 0; r < 4; ++r)
            out[((size_t)bt * C_ + cb0 + r) * HW_ + hw0 + tok] = facc[mt][r];
    }
}

extern "C" void kernel_launch(void* const* d_in, const int* in_sizes, int n_in,
                              void* d_out, int out_size, void* d_ws, size_t ws_size,
                              hipStream_t stream) {
    (void)in_sizes; (void)n_in; (void)out_size; (void)ws_size;
    const float* x      = (const float*)d_in[0];
    const float* guid   = (const float*)d_in[1];
    const float* protos = (const float*)d_in[2];
    const float* Wq     = (const float*)d_in[3];
    const float* bq     = (const float*)d_in[4];
    const float* Wk     = (const float*)d_in[5];
    const float* bk     = (const float*)d_in[6];
    const float* Wv     = (const float*)d_in[7];
    const float* bv     = (const float*)d_in[8];
    const float* ln1_g  = (const float*)d_in[9];
    const float* ln1_b  = (const float*)d_in[10];
    const float* ln2_g  = (const float*)d_in[11];
    const float* ln2_b  = (const float*)d_in[12];
    const float* W1     = (const float*)d_in[13];
    const float* b1     = (const float*)d_in[14];
    const float* W2     = (const float*)d_in[15];
    const float* b2     = (const float*)d_in[16];
    float* out = (float*)d_out;
    char* wsb  = (char*)d_ws;

    prep_all<<<833, 256, 0, stream>>>(protos, Wk, bk, Wv, bv, Wq, W1, W2,
                                      guid, bq, wsb);
    dim3 grid(HW_ / TOK, T_, B_);
    cat_main<<<grid, 512, 0, stream>>>(x, ln1_g, ln1_b, ln2_g, ln2_b,
                                       b1, b2, wsb, out);
}